// Round 7
// baseline (148.201 us; speedup 1.0000x reference)
//
#include <hip/hip_runtime.h>
#include <stdint.h>

// Problem constants
#define B_   16
#define D_   256
#define T_   4096
#define K_   1024
#define N_   (B_ * T_)      // 65536 points
#define BP   128            // points per block (R7)

typedef __attribute__((ext_vector_type(4))) float floatx4;
typedef __attribute__((ext_vector_type(2))) float floatx2;
typedef __attribute__((ext_vector_type(2))) long longx2;

// ---- Kernel 0: emb fp32 -> fp8 e4m3 (scaled x1024), stored in PIECE order:
// tile ct = codes [ct*16, ct*16+16), 4 KB = 4 pieces of 1 KB. Byte for
// (code c, dim d): ct=c>>4, ml=c&15, kk=d>>5, quad=(d>>3)&3, b=d&7 at
//   ct*4096 + (kk>>1)*1024 + (quad*16+ml)*16 + (kk&1)*8 + b
// esqh[c] = 1024*0.5*||e_exact||^2. Also zeroes loss.
__global__ __launch_bounds__(256) void emb_prep(const float* __restrict__ emb,
                                                uint32_t* __restrict__ embf8,
                                                float* __restrict__ esqh,
                                                float* __restrict__ lossp) {
    int w = threadIdx.x >> 6, lane = threadIdx.x & 63;
    int k = blockIdx.x * 4 + w;                       // one wave per code row
    float4 v = ((const float4*)emb)[k * 64 + lane];   // d0 = lane*4
    float a0 = v.x * 1024.f, a1 = v.y * 1024.f, a2 = v.z * 1024.f, a3 = v.w * 1024.f;
    int p = __builtin_amdgcn_cvt_pk_fp8_f32(a0, a1, 0, false);
    p = __builtin_amdgcn_cvt_pk_fp8_f32(a2, a3, p, true);
    int kk = lane >> 3, quad = (lane >> 1) & 3;       // from d0 = lane*4
    int widx = (k >> 4) * 1024 + (kk >> 1) * 256 + (quad * 16 + (k & 15)) * 4
             + (kk & 1) * 2 + (lane & 1);
    embf8[widx] = (uint32_t)p;
    float ss = a0 * a0 + a1 * a1 + a2 * a2 + a3 * a3;   // exact (pre-fp8) scaled norm
    #pragma unroll
    for (int off = 32; off; off >>= 1) ss += __shfl_xor(ss, off, 64);
    if (lane == 0) esqh[k] = ss * (0.5f / 1024.f);      // = 1024 * 0.5*||e||^2
    if (blockIdx.x == 0 && threadIdx.x == 0) *lossp = 0.f;
}

// ---- Main kernel (R7: codebook-in-registers inversion) ----
// R0/R4/R6 all plateaued ~50us with MfmaUtil ~25%: the B-stream (embf8
// re-read per k-tile, 8KB/point) = 2MB/CU through L2 ~= the MFMA floor
// itself, serialized per-wave as wait-L2 -> MFMA -> VALU. R7 removes the
// stream: 1 code costs 1 VGPR/lane (256B/wave), so 8 waves x 128 codes =
// WHOLE codebook in registers, loaded ONCE (256KB/block; 16x less L2).
// The k-loop's only memory op is 8 ds_read_b64/pt-tile (xs swizzle,
// double-buffered under 64 MFMAs). Wave w: all 8 pt-tiles x codes
// [w*128,(w+1)*128) as 8 chains x 8 k-steps; min over the 8 waves'
// candidates merged through wvals[8][BP] at the end.
// Regs: bfr 128 + afrA/B 32 + acc 32 + ehr 8 + misc ~20 ~= 220 < 256 cap
// at launch_bounds(512,2); 1 resident block/CU, grid 512 -> 2 generations.
// xs swizzle identical to prior rounds (s-generic: hf(pnt)=s&1 for
// pnt=s*16+ml). Chain k-order 0..7 == R0's accumulate order; fminf is
// order-independent -> numerics identical (absmax 0.001953125).
// Argmin: packed float, low 10 mantissa bits = code index (K=1024).
__global__ __launch_bounds__(512, 2) void vq_main(const float* __restrict__ z,
                                                  const uint32_t* __restrict__ embf8,
                                                  const float* __restrict__ esqh,
                                                  float* __restrict__ out0,
                                                  float* __restrict__ lossp) {
    __shared__ __align__(16) unsigned char xs[BP * 256];   // 32 KiB
    __shared__ float wvals[8][BP];                         // 4 KiB
    __shared__ int   pidx[BP];
    __shared__ float zred[8];
    __shared__ float lred[2];

    int tid  = threadIdx.x;
    int lane = tid & 63, w = tid >> 6;        // 8 waves
    int ml   = lane & 15, quad = lane >> 4;
    int blk  = blockIdx.x;
    int b    = blk >> 5;                      // 32 blocks per image
    int t0   = (blk & 31) * BP;
    const float* zb = z + (size_t)b * (D_ * T_) + t0;
    float* ob = out0 + (size_t)b * (D_ * T_) + t0;

    // ---- Phase 1: load z [d][t], fp8-convert, transposed+swizzled store ----
    // 512 threads cover 128 points: t = lane + 64*(w&1), dgrp = (w>>1)+4j.
    float zsq = 0.f;
    {
        int t = lane + 64 * (w & 1);
        int hf = (t >> 4) & 1;
        #pragma unroll 2
        for (int j = 0; j < 8; ++j) {
            int dgrp = (w >> 1) + 4 * j;      // 0..31
            int d0 = dgrp * 8;
            float f0 = zb[(d0 + 0) * T_ + t];
            float f1 = zb[(d0 + 1) * T_ + t];
            float f2 = zb[(d0 + 2) * T_ + t];
            float f3 = zb[(d0 + 3) * T_ + t];
            float f4 = zb[(d0 + 4) * T_ + t];
            float f5 = zb[(d0 + 5) * T_ + t];
            float f6 = zb[(d0 + 6) * T_ + t];
            float f7 = zb[(d0 + 7) * T_ + t];
            zsq += f0*f0 + f1*f1 + f2*f2 + f3*f3 + f4*f4 + f5*f5 + f6*f6 + f7*f7;
            uint32_t p0 = (uint32_t)__builtin_amdgcn_cvt_pk_fp8_f32(f0, f1, 0, false);
            p0 = (uint32_t)__builtin_amdgcn_cvt_pk_fp8_f32(f2, f3, (int)p0, true);
            uint32_t p1 = (uint32_t)__builtin_amdgcn_cvt_pk_fp8_f32(f4, f5, 0, false);
            p1 = (uint32_t)__builtin_amdgcn_cvt_pk_fp8_f32(f6, f7, (int)p1, true);
            int c = dgrp >> 1, h = dgrp & 1;
            *(uint2*)&xs[t * 256 + ((c ^ (t & 15)) << 4) + ((h ^ hf) << 3)] =
                make_uint2(p0, p1);
        }
    }

    // ---- B-load: wave w holds codes [w*128, (w+1)*128) in 128 VGPRs ----
    long bfr[8][8];        // [code-tile][k-frag]
    float ehr[8];
    {
        const char* ebW = (const char*)embf8 + (size_t)(w * 8) * 4096 + (size_t)lane * 16;
        #pragma unroll
        for (int ct = 0; ct < 8; ++ct) {
            #pragma unroll
            for (int i = 0; i < 4; ++i) {
                longx2 q = *(const longx2*)(ebW + ct * 4096 + i * 1024);
                bfr[ct][2 * i]     = q[0];
                bfr[ct][2 * i + 1] = q[1];
            }
            ehr[ct] = esqh[(w * 8 + ct) * 16 + ml];
        }
    }
    __syncthreads();

    const floatx4 zv = {0.f, 0.f, 0.f, 0.f};
    const unsigned hi_mask = 0xFFFFFC00u;
    int cb_base = w * 128 + ml;

#define LOAD_AFR(AFR, S)                                                        \
    {                                                                           \
        int pnt = (S) * 16 + ml;                                                \
        _Pragma("unroll")                                                       \
        for (int kk = 0; kk < 8; ++kk) {                                        \
            int c = 2 * kk + (quad >> 1), h = quad & 1;                         \
            AFR[kk] = *(const long*)&xs[pnt * 256 + ((c ^ ml) << 4)             \
                                        + ((h ^ ((S) & 1)) << 3)];              \
        }                                                                       \
    }

// One 16-point tile vs this wave's 128 codes: 64 MFMA (8 chains x 8 k),
// epilogue pack+min, in-wave reduce over 16 code-lanes, publish.
#define PT_TILE(AFR, S)                                                         \
    {                                                                           \
        floatx4 acc[8];                                                         \
        _Pragma("unroll")                                                       \
        for (int ct = 0; ct < 8; ++ct)                                          \
            acc[ct] = __builtin_amdgcn_mfma_f32_16x16x32_fp8_fp8(AFR[0], bfr[ct][0], zv, 0, 0, 0); \
        _Pragma("unroll")                                                       \
        for (int kk = 1; kk < 8; ++kk) {                                        \
            _Pragma("unroll")                                                   \
            for (int ct = 0; ct < 8; ++ct)                                      \
                acc[ct] = __builtin_amdgcn_mfma_f32_16x16x32_fp8_fp8(AFR[kk], bfr[ct][kk], acc[ct], 0, 0, 0); \
        }                                                                       \
        float bvr[4] = {1e30f, 1e30f, 1e30f, 1e30f};                            \
        _Pragma("unroll")                                                       \
        for (int ct = 0; ct < 8; ++ct) {                                        \
            unsigned cb = (unsigned)(cb_base + ct * 16);                        \
            _Pragma("unroll")                                                   \
            for (int i = 0; i < 4; ++i) {                                       \
                float dd = ehr[ct] - acc[ct][i];                                \
                bvr[i] = fminf(bvr[i], __uint_as_float((__float_as_uint(dd) & hi_mask) | cb)); \
            }                                                                   \
        }                                                                       \
        _Pragma("unroll")                                                       \
        for (int i = 0; i < 4; ++i) {                                           \
            float v = bvr[i];                                                   \
            _Pragma("unroll")                                                   \
            for (int off = 1; off < 16; off <<= 1)                              \
                v = fminf(v, __shfl_xor(v, off, 64));                           \
            if (ml == 0) wvals[w][(S) * 16 + quad * 4 + i] = v;                 \
        }                                                                       \
    }

    // ---- k-phase: 8 pt-tiles, afr double-buffered under the MFMA bursts ----
    long afrA[8], afrB[8];
    LOAD_AFR(afrA, 0)
    #pragma unroll 1
    for (int s = 0; s < 8; s += 2) {
        LOAD_AFR(afrB, s + 1)
        PT_TILE(afrA, s)
        if (s + 2 < 8) LOAD_AFR(afrA, s + 2)
        PT_TILE(afrB, s + 1)
    }

#undef LOAD_AFR
#undef PT_TILE

    // ---- zsq reduce ----
    #pragma unroll
    for (int off = 32; off; off >>= 1) zsq += __shfl_xor(zsq, off, 64);
    if (lane == 0) zred[w] = zsq;
    __syncthreads();

    // ---- merge: min over the 8 waves' candidates, per point ----
    if (tid < BP) {
        int t = tid;
        float wv = wvals[0][t];
        #pragma unroll
        for (int k = 1; k < 8; ++k) wv = fminf(wv, wvals[k][t]);
        pidx[t] = (int)(__float_as_uint(wv) & 1023u);
        float lsum = wv;          // packed float == dist to 2^-13 relative
        #pragma unroll
        for (int off = 32; off; off >>= 1) lsum += __shfl_xor(lsum, off, 64);
        if ((tid & 63) == 0) lred[tid >> 6] = lsum;
    }
    __syncthreads();

    if (tid == 0) {
        float tot = zred[0] + zred[1] + zred[2] + zred[3]
                  + zred[4] + zred[5] + zred[6] + zred[7]
                  + (lred[0] + lred[1]) * (2.0f / 1024.f);
        atomicAdd(lossp, tot * (1.25f / 16777216.0f));   // 1.25/(N*D)
    }

    // ---- Phase 4a: gather winning fp8 rows into xs (piece layout) ----
    #pragma unroll
    for (int m = 0; m < 4; ++m) {
        int t = (tid >> 4) + 32 * m;      // 0..127
        int g = tid & 15;                 // chunk: piece i=g>>2, q=g&3
        int code = pidx[t];
        const char* src = (const char*)embf8 + (size_t)(code >> 4) * 4096
                        + (g >> 2) * 1024 + ((g & 3) * 16 + (code & 15)) * 16;
        uint4 v = *(const uint4*)src;
        *(uint4*)&xs[t * 256 + ((g ^ (t & 15)) << 4)] = v;
    }
    __syncthreads();

    // ---- Phase 4b: dequant + transpose-write (piece-order byte decode) ----
    {
        int t = tid & 127, wq = tid >> 7;   // wq 0..3
        #pragma unroll
        for (int jj = 0; jj < 4; ++jj) {
            int g = wq + 4 * jj;            // 16-byte chunk 0..15
            uint4 v = *(const uint4*)&xs[t * 256 + ((g ^ (t & 15)) << 4)];
            uint32_t wd[4] = {v.x, v.y, v.z, v.w};
            #pragma unroll
            for (int u = 0; u < 4; ++u) {
                int kk = (g >> 2) * 2 + (u >> 1);
                int d0 = kk * 32 + (g & 3) * 8 + (u & 1) * 4;
                floatx2 lo = __builtin_amdgcn_cvt_pk_f32_fp8((int)wd[u], false);
                floatx2 hi = __builtin_amdgcn_cvt_pk_f32_fp8((int)wd[u], true);
                ob[(d0 + 0) * T_ + t] = lo[0] * (1.f / 1024.f);
                ob[(d0 + 1) * T_ + t] = lo[1] * (1.f / 1024.f);
                ob[(d0 + 2) * T_ + t] = hi[0] * (1.f / 1024.f);
                ob[(d0 + 3) * T_ + t] = hi[1] * (1.f / 1024.f);
            }
        }
    }
}

extern "C" void kernel_launch(void* const* d_in, const int* in_sizes, int n_in,
                              void* d_out, int out_size, void* d_ws, size_t ws_size,
                              hipStream_t stream) {
    (void)in_sizes; (void)n_in; (void)out_size; (void)ws_size;
    const float* z   = (const float*)d_in[0];
    const float* emb = (const float*)d_in[1];

    uint32_t* embf8 = (uint32_t*)d_ws;                              // 256 KiB
    float*    esqh  = (float*)((char*)d_ws + (size_t)K_ * D_);      // 4 KiB

    float* out0  = (float*)d_out;
    float* lossp = out0 + (size_t)N_ * D_;

    emb_prep<<<K_ / 4, 256, 0, stream>>>(emb, embf8, esqh, lossp);
    vq_main<<<N_ / BP, 512, 0, stream>>>(z, embf8, esqh, out0, lossp);
}